// Round 2
// baseline (345.097 us; speedup 1.0000x reference)
//
#include <hip/hip_runtime.h>
#include <math.h>

// Problem constants (fixed by setup_inputs)
constexpr int B  = 8;
constexpr int CF = 256;
constexpr int HF = 128;
constexpr int WF = 128;
constexpr int HP = 512;
constexpr int WP = 512;
constexpr long long NTOT = (long long)B * CF * HF * WF;   // 33,554,432

// ws layout (bytes):
//   [0, 16)            : double sum, double sumsq
//   [256, 256+512K)    : D_h   (8*128*128 floats)  (also holds pooled mask pre-dilate)
//   [IMG_OFF, +1.5M)   : img_ds (8*3*128*128 floats)
constexpr size_t DH_OFF  = 256;
constexpr size_t IMG_OFF = DH_OFF + (size_t)B * HF * WF * sizeof(float);

__global__ void k_init(double* acc) {
    if (threadIdx.x < 2) acc[threadIdx.x] = 0.0;
}

// Pass 1: global sum / sumsq of F_in (double accumulation, one atomic per block)
__global__ void k_reduce(const float* __restrict__ F, double* __restrict__ acc) {
    long long i0 = ((long long)blockIdx.x * blockDim.x + threadIdx.x) * 4;
    long long stride = (long long)gridDim.x * blockDim.x * 4;
    double s = 0.0, q = 0.0;
    for (long long i = i0; i < NTOT; i += stride) {
        float4 v = *(const float4*)(F + i);
        s += (double)v.x + (double)v.y + (double)v.z + (double)v.w;
        q += (double)v.x * v.x + (double)v.y * v.y +
             (double)v.z * v.z + (double)v.w * v.w;
    }
    // wave-64 reduce
    for (int off = 32; off > 0; off >>= 1) {
        s += __shfl_down(s, off);
        q += __shfl_down(q, off);
    }
    __shared__ double ls[4], lq[4];
    int lane = threadIdx.x & 63, wv = threadIdx.x >> 6;
    if (lane == 0) { ls[wv] = s; lq[wv] = q; }
    __syncthreads();
    if (threadIdx.x == 0) {
        double S = 0.0, Q = 0.0;
        for (int w = 0; w < 4; ++w) { S += ls[w]; Q += lq[w]; }
        atomicAdd(&acc[0], S);
        atomicAdd(&acc[1], Q);
    }
}

// 4x4 avg-pool of img_p (3 ch) and 4x4 max-pool of mask ch0
__global__ void k_pool(const float* __restrict__ img, const float* __restrict__ mask,
                       float* __restrict__ img_ds, float* __restrict__ mds) {
    int t = blockIdx.x * blockDim.x + threadIdx.x;
    if (t >= B * HF * WF) return;
    int w = t & (WF - 1);
    int h = (t >> 7) & (HF - 1);
    int b = t >> 14;
    for (int c = 0; c < 3; ++c) {
        const float* p = img + (((b * 3 + c) * HP + h * 4) * WP + w * 4);
        float s = 0.0f;
        for (int r = 0; r < 4; ++r) {
            float4 v = *(const float4*)(p + r * WP);
            s += v.x + v.y + v.z + v.w;
        }
        img_ds[(((b * 3 + c)) << 14) | (h << 7) | w] = s * 0.0625f;
    }
    const float* pm = mask + (((b * 3) * HP + h * 4) * WP + w * 4);
    float m = 0.0f;
    for (int r = 0; r < 4; ++r) {
        float4 v = *(const float4*)(pm + r * WP);
        m = fmaxf(m, fmaxf(fmaxf(v.x, v.y), fmaxf(v.z, v.w)));
    }
    mds[t] = m;
}

// 5-iteration masked dilation == capped Chebyshev distance transform, in LDS.
// One block per batch image. set(p) <=> M[p] > 0 (values are 0, 1, or 2^-i).
__global__ void __launch_bounds__(1024) k_dilate(const float* __restrict__ mds,
                                                 float* __restrict__ Dh) {
    __shared__ float M[HF * WF];   // 64 KB
    const int b = blockIdx.x;
    const float* src = mds + b * HF * WF;
    for (int i = threadIdx.x; i < HF * WF; i += 1024) M[i] = src[i];
    __syncthreads();
    float invk = 1.0f;
    for (int it = 1; it <= 5; ++it) {
        invk *= 0.5f;
        unsigned nf = 0;
        for (int j = 0; j < 16; ++j) {
            int p = threadIdx.x + j * 1024;
            if (M[p] != 0.0f) continue;   // already set
            int h = p >> 7, w = p & 127;
            bool any = false;
            for (int dh = -1; dh <= 1; ++dh) {
                int hh = h + dh;
                if (hh < 0 || hh >= HF) continue;
                for (int dw = -1; dw <= 1; ++dw) {
                    int ww = w + dw;
                    if (ww < 0 || ww >= WF) continue;
                    any = any || (M[(hh << 7) | ww] > 0.0f);
                }
            }
            if (any) nf |= (1u << j);
        }
        __syncthreads();
        for (int j = 0; j < 16; ++j)
            if (nf & (1u << j)) M[threadIdx.x + j * 1024] = invk;
        __syncthreads();
    }
    float* dst = Dh + b * HF * WF;
    for (int i = threadIdx.x; i < HF * WF; i += 1024) dst[i] = M[i];
}

// Fused epilogue: out = (F - mean)*rstd * (gamma_hp*D) + beta_hp*D
__global__ void k_final(const float* __restrict__ F,
                        const float* __restrict__ img_ds,
                        const float* __restrict__ Dh,
                        const float* __restrict__ gw, const float* __restrict__ gb,
                        const float* __restrict__ bw, const float* __restrict__ bb,
                        const double* __restrict__ acc,
                        float* __restrict__ out) {
    long long t = (long long)blockIdx.x * blockDim.x + threadIdx.x;
    long long base = t * 4;
    if (base >= NTOT) return;
    int w = (int)(base & 127);
    int h = (int)((base >> 7) & 127);
    int c = (int)((base >> 14) & 255);
    int b = (int)(base >> 22);

    double mean = acc[0] / (double)NTOT;
    double var  = (acc[1] - (double)NTOT * mean * mean) / (double)(NTOT - 1);
    float rstd  = (float)(1.0 / sqrt(var * var + 1e-5));
    float meanf = (float)mean;

    int pix = (b << 14) | (h << 7) | w;
    float4 D = *(const float4*)(Dh + pix);
    const float* ip = img_ds + ((size_t)b * 3 << 14);
    float4 R  = *(const float4*)(ip + ((0 << 14) | (h << 7) | w));
    float4 G  = *(const float4*)(ip + ((1 << 14) | (h << 7) | w));
    float4 Bl = *(const float4*)(ip + ((2 << 14) | (h << 7) | w));

    float g0 = gw[c * 3], g1 = gw[c * 3 + 1], g2 = gw[c * 3 + 2], gbi = gb[c];
    float b0 = bw[c * 3], b1 = bw[c * 3 + 1], b2 = bw[c * 3 + 2], bbi = bb[c];

    float4 Fv = *(const float4*)(F + base);
    float4 o;
    {
        float gam = (R.x * g0 + G.x * g1 + Bl.x * g2 + gbi) * D.x;
        float bet = (R.x * b0 + G.x * b1 + Bl.x * b2 + bbi) * D.x;
        o.x = (Fv.x - meanf) * rstd * gam + bet;
    }
    {
        float gam = (R.y * g0 + G.y * g1 + Bl.y * g2 + gbi) * D.y;
        float bet = (R.y * b0 + G.y * b1 + Bl.y * b2 + bbi) * D.y;
        o.y = (Fv.y - meanf) * rstd * gam + bet;
    }
    {
        float gam = (R.z * g0 + G.z * g1 + Bl.z * g2 + gbi) * D.z;
        float bet = (R.z * b0 + G.z * b1 + Bl.z * b2 + bbi) * D.z;
        o.z = (Fv.z - meanf) * rstd * gam + bet;
    }
    {
        float gam = (R.w * g0 + G.w * g1 + Bl.w * g2 + gbi) * D.w;
        float bet = (R.w * b0 + G.w * b1 + Bl.w * b2 + bbi) * D.w;
        o.w = (Fv.w - meanf) * rstd * gam + bet;
    }
    *(float4*)(out + base) = o;
}

extern "C" void kernel_launch(void* const* d_in, const int* in_sizes, int n_in,
                              void* d_out, int out_size, void* d_ws, size_t ws_size,
                              hipStream_t stream) {
    const float* F_in  = (const float*)d_in[0];
    const float* img_p = (const float*)d_in[1];
    const float* mask  = (const float*)d_in[2];
    const float* gw    = (const float*)d_in[3];
    const float* gb    = (const float*)d_in[4];
    const float* bw    = (const float*)d_in[5];
    const float* bb    = (const float*)d_in[6];
    float* out = (float*)d_out;

    double* acc    = (double*)d_ws;
    float*  Dh     = (float*)((char*)d_ws + DH_OFF);
    float*  img_ds = (float*)((char*)d_ws + IMG_OFF);

    k_init<<<1, 64, 0, stream>>>(acc);
    k_reduce<<<2048, 256, 0, stream>>>(F_in, acc);
    // pooled mask is written into the Dh region; k_dilate then transforms it in place
    k_pool<<<(B * HF * WF + 255) / 256, 256, 0, stream>>>(img_p, mask, img_ds, Dh);
    k_dilate<<<B, 1024, 0, stream>>>(Dh, Dh);
    k_final<<<(int)((NTOT / 4 + 255) / 256), 256, 0, stream>>>(
        F_in, img_ds, Dh, gw, gb, bw, bb, acc, out);
}

// Round 3
// 310.224 us; speedup vs baseline: 1.1124x; 1.1124x over previous
//
#include <hip/hip_runtime.h>
#include <math.h>

// Problem constants (fixed by setup_inputs)
constexpr int B  = 8;
constexpr int CF = 256;
constexpr int HF = 128;
constexpr int WF = 128;
constexpr int HP = 512;
constexpr int WP = 512;
constexpr long long NTOT = (long long)B * CF * HF * WF;   // 33,554,432

// ws layout (bytes):
//   [0, 8)              : float meanf, float rstd       (persists to k_final)
//   [256, 256+512K)     : D_h (8*128*128 f32) -- pooled mask, dilated in place
//   [IMG_OFF, +1.5M)    : img_ds (8*3*128*128 f32)
//   partials (16 KB) overlap the img_ds region: consumed by k_stats BEFORE
//   k_pool writes img_ds (stream-ordered), so no extra ws needed.
constexpr size_t STATS_OFF = 0;
constexpr size_t DH_OFF    = 256;
constexpr size_t IMG_OFF   = DH_OFF + (size_t)B * HF * WF * sizeof(float);

constexpr int RBLOCKS  = 1024;
constexpr int RTHREADS = 256;

// Pass 1: per-block partial sum/sumsq with 8 loads in flight per thread.
// S = RBLOCKS*RTHREADS*4 = 1,048,576 floats; NTOT / (8S) = 4 exact iterations.
__global__ void __launch_bounds__(RTHREADS) k_reduce(const float* __restrict__ F,
                                                     double2* __restrict__ part) {
    const long long tid = (long long)blockIdx.x * RTHREADS + threadIdx.x;
    const long long S  = (long long)RBLOCKS * RTHREADS * 4;
    double s0 = 0, s1 = 0, s2 = 0, s3 = 0;
    double q0 = 0, q1 = 0, q2 = 0, q3 = 0;
    for (long long base = tid * 4; base < NTOT; base += 8 * S) {
        float4 v0 = *(const float4*)(F + base + 0 * S);
        float4 v1 = *(const float4*)(F + base + 1 * S);
        float4 v2 = *(const float4*)(F + base + 2 * S);
        float4 v3 = *(const float4*)(F + base + 3 * S);
        float4 v4 = *(const float4*)(F + base + 4 * S);
        float4 v5 = *(const float4*)(F + base + 5 * S);
        float4 v6 = *(const float4*)(F + base + 6 * S);
        float4 v7 = *(const float4*)(F + base + 7 * S);
        s0 += (double)v0.x + (double)v0.y + (double)v0.z + (double)v0.w;
        q0 += (double)v0.x * v0.x + (double)v0.y * v0.y + (double)v0.z * v0.z + (double)v0.w * v0.w;
        s1 += (double)v1.x + (double)v1.y + (double)v1.z + (double)v1.w;
        q1 += (double)v1.x * v1.x + (double)v1.y * v1.y + (double)v1.z * v1.z + (double)v1.w * v1.w;
        s2 += (double)v2.x + (double)v2.y + (double)v2.z + (double)v2.w;
        q2 += (double)v2.x * v2.x + (double)v2.y * v2.y + (double)v2.z * v2.z + (double)v2.w * v2.w;
        s3 += (double)v3.x + (double)v3.y + (double)v3.z + (double)v3.w;
        q3 += (double)v3.x * v3.x + (double)v3.y * v3.y + (double)v3.z * v3.z + (double)v3.w * v3.w;
        s0 += (double)v4.x + (double)v4.y + (double)v4.z + (double)v4.w;
        q0 += (double)v4.x * v4.x + (double)v4.y * v4.y + (double)v4.z * v4.z + (double)v4.w * v4.w;
        s1 += (double)v5.x + (double)v5.y + (double)v5.z + (double)v5.w;
        q1 += (double)v5.x * v5.x + (double)v5.y * v5.y + (double)v5.z * v5.z + (double)v5.w * v5.w;
        s2 += (double)v6.x + (double)v6.y + (double)v6.z + (double)v6.w;
        q2 += (double)v6.x * v6.x + (double)v6.y * v6.y + (double)v6.z * v6.z + (double)v6.w * v6.w;
        s3 += (double)v7.x + (double)v7.y + (double)v7.z + (double)v7.w;
        q3 += (double)v7.x * v7.x + (double)v7.y * v7.y + (double)v7.z * v7.z + (double)v7.w * v7.w;
    }
    double s = (s0 + s1) + (s2 + s3);
    double q = (q0 + q1) + (q2 + q3);
    for (int off = 32; off > 0; off >>= 1) {
        s += __shfl_down(s, off);
        q += __shfl_down(q, off);
    }
    __shared__ double ls[4], lq[4];
    int lane = threadIdx.x & 63, wv = threadIdx.x >> 6;
    if (lane == 0) { ls[wv] = s; lq[wv] = q; }
    __syncthreads();
    if (threadIdx.x == 0) {
        double S_ = 0.0, Q_ = 0.0;
        for (int w = 0; w < 4; ++w) { S_ += ls[w]; Q_ += lq[w]; }
        part[blockIdx.x] = make_double2(S_, Q_);
    }
}

// Reduce the 1024 partials; emit meanf / rstd as floats (deterministic, no atomics).
__global__ void k_stats(const double2* __restrict__ part, float* __restrict__ stats) {
    double s = 0.0, q = 0.0;
    for (int i = threadIdx.x; i < RBLOCKS; i += 256) {
        double2 p = part[i];
        s += p.x; q += p.y;
    }
    for (int off = 32; off > 0; off >>= 1) {
        s += __shfl_down(s, off);
        q += __shfl_down(q, off);
    }
    __shared__ double ls[4], lq[4];
    int lane = threadIdx.x & 63, wv = threadIdx.x >> 6;
    if (lane == 0) { ls[wv] = s; lq[wv] = q; }
    __syncthreads();
    if (threadIdx.x == 0) {
        double S_ = 0.0, Q_ = 0.0;
        for (int w = 0; w < 4; ++w) { S_ += ls[w]; Q_ += lq[w]; }
        double mean = S_ / (double)NTOT;
        double var  = (Q_ - (double)NTOT * mean * mean) / (double)(NTOT - 1);
        stats[0] = (float)mean;
        stats[1] = (float)(1.0 / sqrt(var * var + 1e-5));
    }
}

// 4x4 avg-pool of img_p (3 ch) and 4x4 max-pool of mask ch0
__global__ void k_pool(const float* __restrict__ img, const float* __restrict__ mask,
                       float* __restrict__ img_ds, float* __restrict__ mds) {
    int t = blockIdx.x * blockDim.x + threadIdx.x;
    if (t >= B * HF * WF) return;
    int w = t & (WF - 1);
    int h = (t >> 7) & (HF - 1);
    int b = t >> 14;
    for (int c = 0; c < 3; ++c) {
        const float* p = img + (((b * 3 + c) * HP + h * 4) * WP + w * 4);
        float s = 0.0f;
        for (int r = 0; r < 4; ++r) {
            float4 v = *(const float4*)(p + r * WP);
            s += v.x + v.y + v.z + v.w;
        }
        img_ds[(((b * 3 + c)) << 14) | (h << 7) | w] = s * 0.0625f;
    }
    const float* pm = mask + (((b * 3) * HP + h * 4) * WP + w * 4);
    float m = 0.0f;
    for (int r = 0; r < 4; ++r) {
        float4 v = *(const float4*)(pm + r * WP);
        m = fmaxf(m, fmaxf(fmaxf(v.x, v.y), fmaxf(v.z, v.w)));
    }
    mds[t] = m;
}

// 5-iteration masked dilation == capped Chebyshev distance transform, in LDS.
__global__ void __launch_bounds__(1024) k_dilate(const float* __restrict__ mds,
                                                 float* __restrict__ Dh) {
    __shared__ float M[HF * WF];   // 64 KB
    const int b = blockIdx.x;
    const float* src = mds + b * HF * WF;
    for (int i = threadIdx.x; i < HF * WF; i += 1024) M[i] = src[i];
    __syncthreads();
    float invk = 1.0f;
    for (int it = 1; it <= 5; ++it) {
        invk *= 0.5f;
        unsigned nf = 0;
        for (int j = 0; j < 16; ++j) {
            int p = threadIdx.x + j * 1024;
            if (M[p] != 0.0f) continue;
            int h = p >> 7, w = p & 127;
            bool any = false;
            for (int dh = -1; dh <= 1; ++dh) {
                int hh = h + dh;
                if (hh < 0 || hh >= HF) continue;
                for (int dw = -1; dw <= 1; ++dw) {
                    int ww = w + dw;
                    if (ww < 0 || ww >= WF) continue;
                    any = any || (M[(hh << 7) | ww] > 0.0f);
                }
            }
            if (any) nf |= (1u << j);
        }
        __syncthreads();
        for (int j = 0; j < 16; ++j)
            if (nf & (1u << j)) M[threadIdx.x + j * 1024] = invk;
        __syncthreads();
    }
    float* dst = Dh + b * HF * WF;
    for (int i = threadIdx.x; i < HF * WF; i += 1024) dst[i] = M[i];
}

// Fused epilogue: out = (F - mean)*rstd * (gamma_hp*D) + beta_hp*D
__global__ void k_final(const float* __restrict__ F,
                        const float* __restrict__ img_ds,
                        const float* __restrict__ Dh,
                        const float* __restrict__ gw, const float* __restrict__ gb,
                        const float* __restrict__ bw, const float* __restrict__ bb,
                        const float* __restrict__ stats,
                        float* __restrict__ out) {
    long long t = (long long)blockIdx.x * blockDim.x + threadIdx.x;
    long long base = t * 4;
    if (base >= NTOT) return;
    int w = (int)(base & 127);
    int h = (int)((base >> 7) & 127);
    int c = (int)((base >> 14) & 255);
    int b = (int)(base >> 22);

    float meanf = stats[0];
    float rstd  = stats[1];

    int pix = (b << 14) | (h << 7) | w;
    float4 D = *(const float4*)(Dh + pix);
    const float* ip = img_ds + ((size_t)b * 3 << 14);
    float4 R  = *(const float4*)(ip + ((0 << 14) | (h << 7) | w));
    float4 G  = *(const float4*)(ip + ((1 << 14) | (h << 7) | w));
    float4 Bl = *(const float4*)(ip + ((2 << 14) | (h << 7) | w));

    float g0 = gw[c * 3], g1 = gw[c * 3 + 1], g2 = gw[c * 3 + 2], gbi = gb[c];
    float b0 = bw[c * 3], b1 = bw[c * 3 + 1], b2 = bw[c * 3 + 2], bbi = bb[c];

    float4 Fv = *(const float4*)(F + base);
    float4 o;
    {
        float gam = (R.x * g0 + G.x * g1 + Bl.x * g2 + gbi) * D.x;
        float bet = (R.x * b0 + G.x * b1 + Bl.x * b2 + bbi) * D.x;
        o.x = (Fv.x - meanf) * rstd * gam + bet;
    }
    {
        float gam = (R.y * g0 + G.y * g1 + Bl.y * g2 + gbi) * D.y;
        float bet = (R.y * b0 + G.y * b1 + Bl.y * b2 + bbi) * D.y;
        o.y = (Fv.y - meanf) * rstd * gam + bet;
    }
    {
        float gam = (R.z * g0 + G.z * g1 + Bl.z * g2 + gbi) * D.z;
        float bet = (R.z * b0 + G.z * b1 + Bl.z * b2 + bbi) * D.z;
        o.z = (Fv.z - meanf) * rstd * gam + bet;
    }
    {
        float gam = (R.w * g0 + G.w * g1 + Bl.w * g2 + gbi) * D.w;
        float bet = (R.w * b0 + G.w * b1 + Bl.w * b2 + bbi) * D.w;
        o.w = (Fv.w - meanf) * rstd * gam + bet;
    }
    *(float4*)(out + base) = o;
}

extern "C" void kernel_launch(void* const* d_in, const int* in_sizes, int n_in,
                              void* d_out, int out_size, void* d_ws, size_t ws_size,
                              hipStream_t stream) {
    const float* F_in  = (const float*)d_in[0];
    const float* img_p = (const float*)d_in[1];
    const float* mask  = (const float*)d_in[2];
    const float* gw    = (const float*)d_in[3];
    const float* gb    = (const float*)d_in[4];
    const float* bw    = (const float*)d_in[5];
    const float* bb    = (const float*)d_in[6];
    float* out = (float*)d_out;

    float*   stats  = (float*)((char*)d_ws + STATS_OFF);
    float*   Dh     = (float*)((char*)d_ws + DH_OFF);
    float*   img_ds = (float*)((char*)d_ws + IMG_OFF);
    double2* part   = (double2*)img_ds;   // 16 KB, consumed before img_ds is written

    k_reduce<<<RBLOCKS, RTHREADS, 0, stream>>>(F_in, part);
    k_stats<<<1, 256, 0, stream>>>(part, stats);
    k_pool<<<(B * HF * WF + 255) / 256, 256, 0, stream>>>(img_p, mask, img_ds, Dh);
    k_dilate<<<B, 1024, 0, stream>>>(Dh, Dh);
    k_final<<<(int)((NTOT / 4 + 255) / 256), 256, 0, stream>>>(
        F_in, img_ds, Dh, gw, gb, bw, bb, stats, out);
}

// Round 4
// 305.911 us; speedup vs baseline: 1.1281x; 1.0141x over previous
//
#include <hip/hip_runtime.h>
#include <math.h>

// Problem constants (fixed by setup_inputs)
constexpr int B  = 8;
constexpr int CF = 256;
constexpr int HF = 128;
constexpr int WF = 128;
constexpr int HP = 512;
constexpr int WP = 512;
constexpr long long NTOT = (long long)B * CF * HF * WF;   // 33,554,432

typedef float f4 __attribute__((ext_vector_type(4)));

// ws layout (bytes):
//   [0, 8)              : float meanf, float rstd
//   [256, 256+512K)     : D_h (8*128*128 f32) -- pooled mask, dilated in place
//   [IMG_OFF, +1.5M)    : img_ds (8*3*128*128 f32)
//   [PART_OFF, +32K)    : per-block double2 partials
constexpr size_t STATS_OFF = 0;
constexpr size_t DH_OFF    = 256;
constexpr size_t IMG_OFF   = DH_OFF + (size_t)B * HF * WF * sizeof(float);
constexpr size_t PART_OFF  = IMG_OFF + (size_t)B * 3 * HF * WF * sizeof(float);

constexpr int RBLOCKS  = 2048;
constexpr int RTHREADS = 256;
// total threads = 524288; each thread loads 16 float4 chunks spaced CH_S apart
constexpr long long CH_S = (long long)RBLOCKS * RTHREADS * 4;   // 2,097,152 floats
// 16 * CH_S = NTOT exactly.

// Pass 1: per-block partial sum/sumsq. 16 independent loads in flight/thread,
// f32 pairwise pre-reduction per chunk, 4 independent f64 chains.
__global__ void __launch_bounds__(RTHREADS) k_reduce(const float* __restrict__ F,
                                                     double2* __restrict__ part) {
    const long long tid = (long long)blockIdx.x * RTHREADS + threadIdx.x;
    const float* p = F + tid * 4;
    f4 v[16];
#pragma unroll
    for (int k = 0; k < 16; ++k)
        v[k] = *(const f4*)(p + k * CH_S);
    double s0 = 0, s1 = 0, s2 = 0, s3 = 0;
    double q0 = 0, q1 = 0, q2 = 0, q3 = 0;
#pragma unroll
    for (int k = 0; k < 16; k += 4) {
        {
            f4 w = v[k + 0];
            s0 += (double)((w.x + w.y) + (w.z + w.w));
            q0 += (double)((w.x * w.x + w.y * w.y) + (w.z * w.z + w.w * w.w));
        }
        {
            f4 w = v[k + 1];
            s1 += (double)((w.x + w.y) + (w.z + w.w));
            q1 += (double)((w.x * w.x + w.y * w.y) + (w.z * w.z + w.w * w.w));
        }
        {
            f4 w = v[k + 2];
            s2 += (double)((w.x + w.y) + (w.z + w.w));
            q2 += (double)((w.x * w.x + w.y * w.y) + (w.z * w.z + w.w * w.w));
        }
        {
            f4 w = v[k + 3];
            s3 += (double)((w.x + w.y) + (w.z + w.w));
            q3 += (double)((w.x * w.x + w.y * w.y) + (w.z * w.z + w.w * w.w));
        }
    }
    double s = (s0 + s1) + (s2 + s3);
    double q = (q0 + q1) + (q2 + q3);
    for (int off = 32; off > 0; off >>= 1) {
        s += __shfl_down(s, off);
        q += __shfl_down(q, off);
    }
    __shared__ double ls[4], lq[4];
    int lane = threadIdx.x & 63, wv = threadIdx.x >> 6;
    if (lane == 0) { ls[wv] = s; lq[wv] = q; }
    __syncthreads();
    if (threadIdx.x == 0) {
        double S_ = 0.0, Q_ = 0.0;
        for (int w = 0; w < 4; ++w) { S_ += ls[w]; Q_ += lq[w]; }
        part[blockIdx.x] = make_double2(S_, Q_);
    }
}

// 4x4 avg-pool of img_p (3 ch) and 4x4 max-pool of mask ch0
__global__ void k_pool(const float* __restrict__ img, const float* __restrict__ mask,
                       float* __restrict__ img_ds, float* __restrict__ mds) {
    int t = blockIdx.x * blockDim.x + threadIdx.x;
    if (t >= B * HF * WF) return;
    int w = t & (WF - 1);
    int h = (t >> 7) & (HF - 1);
    int b = t >> 14;
    for (int c = 0; c < 3; ++c) {
        const float* p = img + (((b * 3 + c) * HP + h * 4) * WP + w * 4);
        float s = 0.0f;
        for (int r = 0; r < 4; ++r) {
            f4 v = *(const f4*)(p + r * WP);
            s += v.x + v.y + v.z + v.w;
        }
        img_ds[(((b * 3 + c)) << 14) | (h << 7) | w] = s * 0.0625f;
    }
    const float* pm = mask + (((b * 3) * HP + h * 4) * WP + w * 4);
    float m = 0.0f;
    for (int r = 0; r < 4; ++r) {
        f4 v = *(const f4*)(pm + r * WP);
        m = fmaxf(m, fmaxf(fmaxf(v.x, v.y), fmaxf(v.z, v.w)));
    }
    mds[t] = m;
}

// blocks 0..7: 5-iter masked dilation (capped Chebyshev DT) in LDS, in place.
// block 8: reduce the 2048 double2 partials -> stats {meanf, rstd}.
__global__ void __launch_bounds__(1024) k_dilate_stats(float* __restrict__ Dh,
                                                       const double2* __restrict__ part,
                                                       float* __restrict__ stats) {
    if (blockIdx.x == 8) {
        double s = 0.0, q = 0.0;
        for (int i = threadIdx.x; i < RBLOCKS; i += 1024) {
            double2 p = part[i];
            s += p.x; q += p.y;
        }
        for (int off = 32; off > 0; off >>= 1) {
            s += __shfl_down(s, off);
            q += __shfl_down(q, off);
        }
        __shared__ double ls[16], lq[16];
        int lane = threadIdx.x & 63, wv = threadIdx.x >> 6;
        if (lane == 0) { ls[wv] = s; lq[wv] = q; }
        __syncthreads();
        if (threadIdx.x == 0) {
            double S_ = 0.0, Q_ = 0.0;
            for (int w = 0; w < 16; ++w) { S_ += ls[w]; Q_ += lq[w]; }
            double mean = S_ / (double)NTOT;
            double var  = (Q_ - (double)NTOT * mean * mean) / (double)(NTOT - 1);
            stats[0] = (float)mean;
            stats[1] = (float)(1.0 / sqrt(var * var + 1e-5));
        }
        return;
    }
    __shared__ float M[HF * WF];   // 64 KB
    const int b = blockIdx.x;
    float* img = Dh + b * HF * WF;
    for (int i = threadIdx.x; i < HF * WF; i += 1024) M[i] = img[i];
    __syncthreads();
    float invk = 1.0f;
    for (int it = 1; it <= 5; ++it) {
        invk *= 0.5f;
        unsigned nf = 0;
        for (int j = 0; j < 16; ++j) {
            int p = threadIdx.x + j * 1024;
            if (M[p] != 0.0f) continue;
            int h = p >> 7, w = p & 127;
            bool any = false;
            for (int dh = -1; dh <= 1; ++dh) {
                int hh = h + dh;
                if (hh < 0 || hh >= HF) continue;
                for (int dw = -1; dw <= 1; ++dw) {
                    int ww = w + dw;
                    if (ww < 0 || ww >= WF) continue;
                    any = any || (M[(hh << 7) | ww] > 0.0f);
                }
            }
            if (any) nf |= (1u << j);
        }
        __syncthreads();
        for (int j = 0; j < 16; ++j)
            if (nf & (1u << j)) M[threadIdx.x + j * 1024] = invk;
        __syncthreads();
    }
    for (int i = threadIdx.x; i < HF * WF; i += 1024) img[i] = M[i];
}

// Fused epilogue, channel-grouped: each thread does 4 w-elems x 8 channels,
// reusing the per-pixel D/R/G/B gather across channels. NT load/store on the
// big streams to keep L3 for the pixel tables.
constexpr int CGRP = 8;
__global__ void __launch_bounds__(256) k_final(const float* __restrict__ F,
                        const float* __restrict__ img_ds,
                        const float* __restrict__ Dh,
                        const float* __restrict__ gw, const float* __restrict__ gb,
                        const float* __restrict__ bw, const float* __restrict__ bb,
                        const float* __restrict__ stats,
                        float* __restrict__ out) {
    long long tid = (long long)blockIdx.x * blockDim.x + threadIdx.x;
    // tid in [0, 1048576): iw(32) | ih(128) | icg(32) | ib(8)
    int iw  = (int)(tid & 31);
    int ih  = (int)((tid >> 5) & 127);
    int icg = (int)((tid >> 12) & 31);
    int ib  = (int)(tid >> 17);
    int w   = iw * 4;
    int c0  = icg * CGRP;

    float meanf = stats[0];
    float rstd  = stats[1];

    int pixoff = (ih << 7) | w;
    int pix = (ib << 14) | pixoff;
    f4 D = *(const f4*)(Dh + pix);
    const float* ip = img_ds + ((size_t)ib * 3 << 14);
    f4 R  = *(const f4*)(ip + ((0 << 14) | pixoff));
    f4 G  = *(const f4*)(ip + ((1 << 14) | pixoff));
    f4 Bl = *(const f4*)(ip + ((2 << 14) | pixoff));

    const size_t fbase = (((size_t)(ib * CF + c0)) << 14) + pixoff;

    f4 Fv[CGRP];
#pragma unroll
    for (int j = 0; j < CGRP; ++j)
        Fv[j] = __builtin_nontemporal_load((const f4*)(F + fbase + ((size_t)j << 14)));

#pragma unroll
    for (int j = 0; j < CGRP; ++j) {
        int c = c0 + j;
        float g0 = gw[c * 3], g1 = gw[c * 3 + 1], g2 = gw[c * 3 + 2], gbi = gb[c];
        float b0 = bw[c * 3], b1 = bw[c * 3 + 1], b2 = bw[c * 3 + 2], bbi = bb[c];
        f4 o;
        {
            float gam = (R.x * g0 + G.x * g1 + Bl.x * g2 + gbi) * D.x;
            float bet = (R.x * b0 + G.x * b1 + Bl.x * b2 + bbi) * D.x;
            o.x = (Fv[j].x - meanf) * rstd * gam + bet;
        }
        {
            float gam = (R.y * g0 + G.y * g1 + Bl.y * g2 + gbi) * D.y;
            float bet = (R.y * b0 + G.y * b1 + Bl.y * b2 + bbi) * D.y;
            o.y = (Fv[j].y - meanf) * rstd * gam + bet;
        }
        {
            float gam = (R.z * g0 + G.z * g1 + Bl.z * g2 + gbi) * D.z;
            float bet = (R.z * b0 + G.z * b1 + Bl.z * b2 + bbi) * D.z;
            o.z = (Fv[j].z - meanf) * rstd * gam + bet;
        }
        {
            float gam = (R.w * g0 + G.w * g1 + Bl.w * g2 + gbi) * D.w;
            float bet = (R.w * b0 + G.w * b1 + Bl.w * b2 + bbi) * D.w;
            o.w = (Fv[j].w - meanf) * rstd * gam + bet;
        }
        __builtin_nontemporal_store(o, (f4*)(out + fbase + ((size_t)j << 14)));
    }
}

extern "C" void kernel_launch(void* const* d_in, const int* in_sizes, int n_in,
                              void* d_out, int out_size, void* d_ws, size_t ws_size,
                              hipStream_t stream) {
    const float* F_in  = (const float*)d_in[0];
    const float* img_p = (const float*)d_in[1];
    const float* mask  = (const float*)d_in[2];
    const float* gw    = (const float*)d_in[3];
    const float* gb    = (const float*)d_in[4];
    const float* bw    = (const float*)d_in[5];
    const float* bb    = (const float*)d_in[6];
    float* out = (float*)d_out;

    float*   stats  = (float*)((char*)d_ws + STATS_OFF);
    float*   Dh     = (float*)((char*)d_ws + DH_OFF);
    float*   img_ds = (float*)((char*)d_ws + IMG_OFF);
    double2* part   = (double2*)((char*)d_ws + PART_OFF);

    k_reduce<<<RBLOCKS, RTHREADS, 0, stream>>>(F_in, part);
    k_pool<<<(B * HF * WF + 255) / 256, 256, 0, stream>>>(img_p, mask, img_ds, Dh);
    k_dilate_stats<<<B + 1, 1024, 0, stream>>>(Dh, part, stats);
    k_final<<<(int)(NTOT / (4 * CGRP) / 256), 256, 0, stream>>>(
        F_in, img_ds, Dh, gw, gb, bw, bb, stats, out);
}